// Round 7
// baseline (325.564 us; speedup 1.0000x reference)
//
#include <hip/hip_runtime.h>
#include <math.h>

#define B_ 4
#define S_ 2
#define P_ 17
#define H_ 128
#define W_ 128
#define M_ 8
#define K_ 10
#define HW_ (H_*W_)
#define PHW_ (P_*HW_)
#define CH_ 34                 // (1+TAG)*P channels in preds
#define G_ 68                  // chunks per (b,s): quarter-channel (4096 elems)
#define C_ 4096                // elements per chunk
#define E_INV_F 0.36787944117144233f
#define LOG2E 1.4426950408889634f
#define SF_ 3.0f
#define INV2SIG 12.5f          // 1/(2*0.2^2)
#define MAXDIST 256.0f         // H+W

#define NBLK (B_*S_*G_)        // 544 total blocks
#define SKEL_CHUNKS 4
#define NBSP (B_*S_*P_)        // 136 ; NBSP*SKEL_CHUNKS == NBLK

// ---- monotone float->u32 map: larger key == larger float ----
__device__ __forceinline__ unsigned int map32(float f) {
    unsigned int u = __float_as_uint(f);
    unsigned int flip = (unsigned int)((int)u >> 31) | 0x80000000u;
    return u ^ flip;
}

// branch-free sorted-desc insert via compare vector
__device__ __forceinline__ void insert10(unsigned long long* a, unsigned long long key) {
    bool c[10];
    #pragma unroll
    for (int j = 0; j < 10; ++j) c[j] = key > a[j];
    #pragma unroll
    for (int j = 9; j >= 1; --j)
        a[j] = c[j-1] ? a[j-1] : (c[j] ? key : a[j]);
    a[0] = c[0] ? key : a[0];
}

__device__ __forceinline__ void merge10(unsigned long long* a, const unsigned long long* b) {
    #pragma unroll
    for (int t = 0; t < 10; ++t) {
        unsigned long long key = b[t];
        if (key > a[9]) insert10(a, key);
    }
}

__device__ __forceinline__ void spin_until(unsigned int* p, unsigned int target) {
    while (__hip_atomic_load(p, __ATOMIC_ACQUIRE, __HIP_MEMORY_SCOPE_AGENT) != target) {
        __builtin_amdgcn_s_sleep(8);
    }
}

// release pattern: all block writes -> device visibility -> tid0 bumps counter
#define BLOCK_RELEASE(CTR)  do { __syncthreads(); __threadfence(); __syncthreads(); \
                                 if (tid == 0) atomicAdd((CTR), 1u); } while (0)

// ============ single fused kernel, 544 blocks x 256 ============
__global__ __launch_bounds__(256, 3) void k_all(const float* __restrict__ preds,
                                                const float* __restrict__ gmask,
                                                const float* __restrict__ gh,
                                                const float* __restrict__ gsk,
                                                const int* __restrict__ kp,
                                                unsigned int* __restrict__ ctr,
                                                unsigned long long* __restrict__ cand,
                                                float* __restrict__ ws_tv,
                                                int* __restrict__ ws_pid,
                                                float* __restrict__ ws_skl,
                                                float* __restrict__ ws_ssx,
                                                float* __restrict__ ws_ssy,
                                                float* __restrict__ ws_det,
                                                float* __restrict__ ws_tag,
                                                float* __restrict__ out) {
    int tid = threadIdx.x;
    int blk = blockIdx.x;
    int wave = tid >> 6, lane = tid & 63;

    __shared__ unsigned long long sm[256*10];          // 20 KB (scan merge / top2 merge)
    __shared__ float s_g[M_*P_], s_vis[M_*P_];
    __shared__ float s_mt[M_], s_val[M_], s_pp[M_];
    __shared__ float sred[4];
    __shared__ float red[4][K_][3];
    __shared__ int   s_last;

    // ================= phase A: scan + det (all blocks), tag (blocks 0..7) ==========
    {
        int bs = blk / G_;
        int c  = blk % G_;
        int p       = c >> 2;
        int quarter = c & 3;
        int b       = bs / S_;
        const float4* base = (const float4*)preds + (size_t)bs*CH_*1024*4 + (size_t)c*1024;
        const float4* gm4p = (const float4*)gmask + (size_t)b*4096 + quarter*1024;
        const float4* gh4p = (const float4*)gh + ((size_t)b*P_ + p)*4096 + quarter*1024;

        unsigned long long a[10];
        #pragma unroll
        for (int j = 0; j < 10; ++j) a[j] = 0ull;
        float det_acc = 0.0f;

        #pragma unroll
        for (int j = 0; j < 4; ++j) {            // 4 float4 per thread = 16 elems
            int q = j*256 + tid;
            float4 hv = base[q];
            float4 gm = gm4p[q];
            float4 gv = gh4p[q];
            unsigned int i0 = (unsigned int)(c*C_ + q*4);
            const float* hvv = &hv.x; const float* gmv = &gm.x; const float* ghv4 = &gv.x;
            #pragma unroll
            for (int cc = 0; cc < 4; ++cc) {
                float hm = hvv[cc];
                unsigned long long key =
                    ((unsigned long long)map32(hm) << 32) | (unsigned int)(~(i0 + cc));
                insert10(a, key);
                float e = exp2f(-fabsf(hm)*LOG2E);
                float r = __builtin_amdgcn_rcpf(1.0f + e);
                float prob = (hm >= 0.0f) ? r : e*r;
                float x = prob * gmv[cc];
                float ghv = ghv4[cc];
                float tt  = (ghv > E_INV_F) ? 1.0f : 0.0f;
                float wgt = 10.0f*tt + ((ghv < E_INV_F) ? 0.5f : 0.0f);
                float lx  = fmaxf(__logf(x),        -100.0f);
                float l1x = fmaxf(__logf(1.0f - x), -100.0f);
                det_acc += wgt * (-(tt*lx + (1.0f - tt)*l1x));
            }
        }
        #pragma unroll
        for (int off = 32; off > 0; off >>= 1) det_acc += __shfl_down(det_acc, off);
        if (lane == 0) sred[wave] = det_acc;
        #pragma unroll
        for (int j = 0; j < 10; ++j) sm[tid*10+j] = a[j];
        __syncthreads();
        if (tid == 0) ws_det[blk] = sred[0] + sred[1] + sred[2] + sred[3];
        for (int st = 128; st >= 1; st >>= 1) {
            if (tid < st) {
                unsigned long long x[10], y[10];
                #pragma unroll
                for (int j = 0; j < 10; ++j) { x[j] = sm[tid*10+j]; y[j] = sm[(tid+st)*10+j]; }
                merge10(x, y);
                #pragma unroll
                for (int j = 0; j < 10; ++j) sm[tid*10+j] = x[j];
            }
            __syncthreads();
        }
        if (tid < 10) cand[(size_t)blk*10 + tid] = sm[tid];
    }
    // tag loss on blocks 0..7 (bs2 = blk)
    if (blk < B_*S_) {
        int bs2 = blk; int b2 = bs2 / S_;
        const float* tagbase = preds + ((size_t)bs2*CH_ + P_)*HW_;
        if (tid < M_*P_) {
            int m = tid / P_; int pp = tid % P_;
            int off = ((b2*M_ + m)*P_ + pp)*2;
            s_g[tid]   = tagbase[kp[off]];
            s_vis[tid] = (kp[off+1] > 0) ? 1.0f : 0.0f;
        }
        __syncthreads();
        if (tid < M_) {
            float cnt = 0.0f, sum = 0.0f;
            for (int pp = 0; pp < P_; pp++) { cnt += s_vis[tid*P_+pp]; sum += s_g[tid*P_+pp]*s_vis[tid*P_+pp]; }
            float safe = fmaxf(cnt, 1.0f);
            float mt = sum / safe;
            s_mt[tid] = mt;
            s_val[tid] = (cnt > 0.0f) ? 1.0f : 0.0f;
            float pl = 0.0f;
            for (int pp = 0; pp < P_; pp++) { float d = s_g[tid*P_+pp] - mt; pl += d*d*s_vis[tid*P_+pp]; }
            s_pp[tid] = pl / safe;
        }
        __syncthreads();
        if (tid == 0) {
            float num = 0.0f;
            for (int m = 0; m < M_; m++) num += s_val[m];
            float pull = 0.0f;
            for (int m = 0; m < M_; m++) pull += s_pp[m]*s_val[m];
            pull = pull / (num + 1e-6f);
            float pmsum = 0.0f;
            for (int i = 0; i < M_; i++)
                for (int j = 0; j < M_; j++) {
                    float d = s_mt[i] - s_mt[j]; d = d*d;
                    pmsum += expf(-d)*s_val[i]*s_val[j];
                }
            float push = (pmsum - num) / ((num - 1.0f)*num + 1e-6f) * 0.5f;
            ws_tag[bs2] = push + pull;
        }
    }
    BLOCK_RELEASE(&ctr[0]);

    // ================= phase B: top-k merge + tv/pid (blocks 0..7) ==========
    if (blk < B_*S_) {
        if (tid == 0) spin_until(&ctr[0], NBLK);
        __syncthreads();
        __threadfence();
        int bs2 = blk; int b2 = bs2 / S_;
        if (tid < 128) {
            if (tid < G_) {
                #pragma unroll
                for (int j = 0; j < 10; ++j) sm[tid*10+j] = cand[((size_t)bs2*G_ + tid)*10 + j];
            } else {
                #pragma unroll
                for (int j = 0; j < 10; ++j) sm[tid*10+j] = 0ull;
            }
        }
        __syncthreads();
        for (int st = 64; st >= 1; st >>= 1) {
            if (tid < st) {
                unsigned long long x[10], y[10];
                #pragma unroll
                for (int j = 0; j < 10; ++j) { x[j] = sm[tid*10+j]; y[j] = sm[(tid+st)*10+j]; }
                merge10(x, y);
                #pragma unroll
                for (int j = 0; j < 10; ++j) sm[tid*10+j] = x[j];
            }
            __syncthreads();
        }
        if (tid < K_) {
            unsigned long long key = sm[tid];
            unsigned int topi = (unsigned int)(~key);
            int part = topi >> 14;
            int rem  = topi & (HW_-1);
            int xi   = rem >> 7;
            int yi   = rem & (W_-1);
            const float* tagbase = preds + ((size_t)bs2*CH_ + P_)*HW_;
            float tv = tagbase[topi];
            float best = INFINITY; int pid = 0;
            for (int m = 0; m < M_; m++) {
                const float* sk = gsk + ((size_t)(b2*M_ + m)*P_ + part)*3;
                float sk1 = sk[1], sk2 = sk[2];
                float vp = (sk2 == 1.0f) ? MAXDIST : 0.0f;
                float d0 = vp + sk1 - (float)xi;
                float d1 = vp + sk2 - (float)yi;
                float dist = sqrtf(d0*d0 + d1*d1 + 1e-12f);
                if (dist < best) { best = dist; pid = m; }
            }
            ws_tv[bs2*K_ + tid]  = tv;
            ws_pid[bs2*K_ + tid] = pid;
        }
        BLOCK_RELEASE(&ctr[8]);
    }
    if (tid == 0) spin_until(&ctr[8], (unsigned int)(B_*S_));
    __syncthreads();
    __threadfence();

    // ================= phase C: skel chunk (all blocks) ==========
    {
        int bid   = blk / SKEL_CHUNKS;
        int chunk = blk % SKEL_CHUNKS;
        int p  = bid % P_;
        int bs = bid / P_;
        const float4* hm4 = (const float4*)(preds + ((size_t)bs*CH_ + p)*HW_);
        const float4* tg4 = (const float4*)(preds + ((size_t)bs*CH_ + P_ + p)*HW_);
        float tv[K_];
        #pragma unroll
        for (int k = 0; k < K_; k++) tv[k] = ws_tv[bs*K_ + k];
        float l[K_], sx[K_], sy[K_];
        #pragma unroll
        for (int k = 0; k < K_; k++) { l[k] = 0.0f; sx[k] = 0.0f; sy[k] = 0.0f; }
        const float C2 = INV2SIG * LOG2E;
        #pragma unroll
        for (int j = 0; j < 4; ++j) {
            int q = chunk*1024 + j*256 + tid;
            float4 hv = hm4[q];
            float4 tg = tg4[q];
            float h  = (float)(q >> 5);
            float w0 = (float)((q*4) & (W_-1));
            const float* hvv = &hv.x; const float* tgv = &tg.x;
            #pragma unroll
            for (int cc = 0; cc < 4; ++cc) {
                float a2 = (SF_*LOG2E) * hvv[cc];
                float tgc = tgv[cc];
                float w = w0 + (float)cc;
                #pragma unroll
                for (int k = 0; k < K_; k++) {
                    float d = tgc - tv[k];
                    float e = exp2f(fmaf(-C2, d*d, a2));
                    l[k] += e;
                    sx[k] = fmaf(e, h, sx[k]);
                    sy[k] = fmaf(e, w, sy[k]);
                }
            }
        }
        #pragma unroll
        for (int k = 0; k < K_; k++) {
            for (int off = 32; off > 0; off >>= 1) {
                l[k]  += __shfl_down(l[k],  off);
                sx[k] += __shfl_down(sx[k], off);
                sy[k] += __shfl_down(sy[k], off);
            }
        }
        if (lane == 0) {
            #pragma unroll
            for (int k = 0; k < K_; k++) {
                red[wave][k][0] = l[k]; red[wave][k][1] = sx[k]; red[wave][k][2] = sy[k];
            }
        }
        __syncthreads();
        if (tid < K_) {
            int k = tid;
            float L  = red[0][k][0] + red[1][k][0] + red[2][k][0] + red[3][k][0];
            float SX = red[0][k][1] + red[1][k][1] + red[2][k][1] + red[3][k][1];
            float SY = red[0][k][2] + red[1][k][2] + red[2][k][2] + red[3][k][2];
            int o = blk*K_ + k;
            ws_skl[o] = L; ws_ssx[o] = SX; ws_ssy[o] = SY;
        }
    }
    // ================= phase D: last block finalizes ==========
    __syncthreads();
    __threadfence();
    __syncthreads();
    if (tid == 0) {
        unsigned int old = atomicAdd(&ctr[16], 1u);
        s_last = (old == NBLK - 1) ? 1 : 0;
    }
    __syncthreads();
    if (s_last) {
        __threadfence();
        float acc = 0.0f;
        for (int i = tid; i < NBLK; i += 256) acc += ws_det[i];
        acc *= (1.0f/(float)(B_*S_*P_*HW_));
        if (tid < B_*S_) acc += ws_tag[tid] * (1.0f/(float)(B_*S_));
        for (int idx = tid; idx < NBSP*K_; idx += 256) {
            int bid = idx / K_;
            int k   = idx % K_;
            int p  = bid % P_;
            int bs = bid / P_;
            int b  = bs / S_;
            float L = 0.0f, SX = 0.0f, SY = 0.0f;
            #pragma unroll
            for (int c = 0; c < SKEL_CHUNKS; ++c) {
                int o = (bid*SKEL_CHUNKS + c)*K_ + k;
                L += ws_skl[o]; SX += ws_ssx[o]; SY += ws_ssy[o];
            }
            float px = SX / L, py = SY / L;
            int pid = ws_pid[bs*K_ + k];
            const float* g = gsk + ((size_t)(b*M_ + pid)*P_ + p)*3;
            float d0 = g[0] - px, d1 = g[1] - py;
            float gate = (g[2] > 0.0f) ? 1.0f : 0.0f;
            float err = sqrtf(d0*d0 + d1*d1 + 1e-12f) * gate;
            float hub = (err < 0.1f) ? err*err : 0.1f*(err - 0.05f);
            acc += hub * (10.0f/(float)(B_*S_*K_*P_));
        }
        #pragma unroll
        for (int off = 32; off > 0; off >>= 1) acc += __shfl_down(acc, off);
        if (lane == 0) sred[wave] = acc;
        __syncthreads();
        if (tid == 0) out[0] = sred[0] + sred[1] + sred[2] + sred[3];
    }
}

extern "C" void kernel_launch(void* const* d_in, const int* in_sizes, int n_in,
                              void* d_out, int out_size, void* d_ws, size_t ws_size,
                              hipStream_t stream) {
    (void)in_sizes; (void)n_in; (void)out_size; (void)ws_size;
    const float* preds = (const float*)d_in[0];
    const float* gmask = (const float*)d_in[1];
    const float* gh    = (const float*)d_in[2];
    const float* gsk   = (const float*)d_in[3];
    const int*   gkp   = (const int*)d_in[4];
    float* out = (float*)d_out;

    unsigned int* ctr = (unsigned int*)d_ws;                         // 256 B control
    char* base = (char*)d_ws + 256;
    unsigned long long* cand = (unsigned long long*)base;            // 5440 u64
    float* ws_tv  = (float*)(cand + (size_t)NBLK*10);                // 80 f
    int*   ws_pid = (int*)(ws_tv + (size_t)B_*S_*K_);                // 80 i
    float* ws_skl = (float*)(ws_pid + (size_t)B_*S_*K_);             // 5440 f
    float* ws_ssx = ws_skl + (size_t)NBLK*K_;
    float* ws_ssy = ws_ssx + (size_t)NBLK*K_;
    float* ws_det = ws_ssy + (size_t)NBLK*K_;                        // 544 f
    float* ws_tag = ws_det + NBLK;                                   // 8 f

    hipMemsetAsync(d_ws, 0, 256, stream);
    hipLaunchKernelGGL(k_all, dim3(NBLK), dim3(256), 0, stream,
                       preds, gmask, gh, gsk, gkp, ctr, cand,
                       ws_tv, ws_pid, ws_skl, ws_ssx, ws_ssy, ws_det, ws_tag, out);
}

// Round 8
// 129.627 us; speedup vs baseline: 2.5116x; 2.5116x over previous
//
#include <hip/hip_runtime.h>
#include <math.h>

#define B_ 4
#define S_ 2
#define P_ 17
#define H_ 128
#define W_ 128
#define M_ 8
#define K_ 10
#define HW_ (H_*W_)
#define PHW_ (P_*HW_)
#define CH_ 34                 // (1+TAG)*P channels in preds
#define G_ 34                  // chunks per (b,s): one half-channel (8192 elems) each
#define C_ 8192                // elements per chunk
#define E_INV_F 0.36787944117144233f
#define LOG2E 1.4426950408889634f
#define SF_ 3.0f
#define INV2SIG 12.5f          // 1/(2*0.2^2)
#define MAXDIST 256.0f         // H+W

#define TOP1_BLOCKS (B_*S_*G_)   // 272
#define DET_BLOCKS  544
#define TAG_BLOCKS  (B_*S_)      // 8
#define MAIN_BLOCKS (TOP1_BLOCKS + DET_BLOCKS + TAG_BLOCKS)

#define SKEL_CHUNKS 4
#define NBSP (B_*S_*P_)                      // 136
#define SKEL_BLOCKS (NBSP*SKEL_CHUNKS)       // 544

// ---- packed sort key: monotone float map (hi) | ~index (lo) ----
__device__ __forceinline__ unsigned int map32(float f) {
    unsigned int u = __float_as_uint(f);
    unsigned int flip = (unsigned int)((int)u >> 31) | 0x80000000u;
    return u ^ flip;
}

// branch-free insert into sorted-descending a[0..9]
__device__ __forceinline__ void insert10(unsigned long long* a, unsigned long long key) {
    #pragma unroll
    for (int j = 9; j >= 1; --j) {
        unsigned long long am1 = a[j-1];
        a[j] = (key > am1) ? am1 : ((key > a[j]) ? key : a[j]);
    }
    a[0] = (key > a[0]) ? key : a[0];
}

__device__ __forceinline__ void merge10(unsigned long long* a, const unsigned long long* b) {
    #pragma unroll
    for (int t = 0; t < 10; ++t) {
        unsigned long long key = b[t];
        if (key > a[9]) insert10(a, key);
    }
}

// ================= fused main kernel: top1 scan | det partial | tag partial ======
__global__ __launch_bounds__(256, 4) void k_main(const float* __restrict__ preds,
                                                 const float* __restrict__ gmask,
                                                 const float* __restrict__ gh,
                                                 const int* __restrict__ kp,
                                                 unsigned long long* __restrict__ cand,
                                                 float* __restrict__ ws_det,
                                                 float* __restrict__ ws_tag) {
    int tid = threadIdx.x;
    if (blockIdx.x < TOP1_BLOCKS) {
        // -------- top-k phase 1: wave-cooperative ballot scan --------
        int bs = blockIdx.x / G_;
        int c  = blockIdx.x % G_;
        int wave = tid >> 6, lane = tid & 63;
        const float4* base = (const float4*)(preds + (size_t)bs*CH_*HW_ + (size_t)c*C_);
        unsigned long long a[10];
        #pragma unroll
        for (int j = 0; j < 10; ++j) a[j] = 0ull;
        for (int j = 0; j < 8; ++j) {                  // wave covers 2048 elements
            int idx4 = wave*512 + j*64 + lane;
            float4 v = base[idx4];
            unsigned int i0 = (unsigned int)(c*C_ + idx4*4);
            const float* vv = &v.x;
            #pragma unroll
            for (int cc = 0; cc < 4; ++cc) {
                unsigned int key32 = map32(vv[cc]);
                unsigned int thr = (unsigned int)(a[9] >> 32);
                unsigned long long mask = __ballot(key32 >= thr);
                if (mask) {
                    unsigned long long kk =
                        ((unsigned long long)key32 << 32) | (unsigned int)(~(i0 + cc));
                    do {
                        int l = (int)__ffsll(mask) - 1;
                        unsigned long long cnd = __shfl(kk, l);
                        if (cnd > a[9]) insert10(a, cnd);
                        mask &= mask - 1;
                    } while (mask);
                }
            }
        }
        __shared__ unsigned long long smw[4][10];
        if (lane == 0) {
            #pragma unroll
            for (int j = 0; j < 10; ++j) smw[wave][j] = a[j];
        }
        __syncthreads();
        if (tid < 2) {
            unsigned long long x[10], y[10];
            #pragma unroll
            for (int j = 0; j < 10; ++j) { x[j] = smw[tid][j]; y[j] = smw[tid+2][j]; }
            merge10(x, y);
            #pragma unroll
            for (int j = 0; j < 10; ++j) smw[tid][j] = x[j];
        }
        __syncthreads();
        if (tid == 0) {
            unsigned long long x[10], y[10];
            #pragma unroll
            for (int j = 0; j < 10; ++j) { x[j] = smw[0][j]; y[j] = smw[1][j]; }
            merge10(x, y);
            #pragma unroll
            for (int j = 0; j < 10; ++j) cand[(size_t)blockIdx.x*10 + j] = x[j];
        }
    } else if (blockIdx.x < TOP1_BLOCKS + DET_BLOCKS) {
        // -------- det loss partial (no atomic; per-block partial to ws) --------
        int dblk = blockIdx.x - TOP1_BLOCKS;
        int t = dblk*256 + tid;
        float acc = 0.0f;
        #pragma unroll
        for (int j = 0; j < 4; ++j) {                  // 4*139264 == N4 exactly
            int q = t + j*(DET_BLOCKS*256);
            int hw4 = q & 4095;
            int t1  = q >> 12;
            int p   = t1 % P_;
            int t2  = t1 / P_;
            float4 hm4 = ((const float4*)preds)[(t2*CH_ + p)*4096 + hw4];
            float4 gm4 = ((const float4*)gmask)[(t2>>1)*4096 + hw4];
            float4 gh4 = ((const float4*)gh)[((t2>>1)*P_ + p)*4096 + hw4];
            const float* hmv = &hm4.x; const float* gmv = &gm4.x; const float* ghv4 = &gh4.x;
            #pragma unroll
            for (int cc = 0; cc < 4; ++cc) {
                float hm = hmv[cc];
                float e = exp2f(-fabsf(hm)*LOG2E);
                float r = __builtin_amdgcn_rcpf(1.0f + e);
                float prob = (hm >= 0.0f) ? r : e*r;
                float x = prob * gmv[cc];
                float ghv = ghv4[cc];
                float tt  = (ghv > E_INV_F) ? 1.0f : 0.0f;
                float wgt = 10.0f*tt + ((ghv < E_INV_F) ? 0.5f : 0.0f);
                float lx  = fmaxf(__logf(x),        -100.0f);
                float l1x = fmaxf(__logf(1.0f - x), -100.0f);
                acc += wgt * (-(tt*lx + (1.0f - tt)*l1x));
            }
        }
        #pragma unroll
        for (int off = 32; off > 0; off >>= 1) acc += __shfl_down(acc, off);
        __shared__ float sred[4];
        int wave = tid >> 6, lane = tid & 63;
        if (lane == 0) sred[wave] = acc;
        __syncthreads();
        if (tid == 0) ws_det[dblk] = sred[0] + sred[1] + sred[2] + sred[3];
    } else {
        // -------- push/pull tag loss partial --------
        int bs = blockIdx.x - (TOP1_BLOCKS + DET_BLOCKS);
        int b = bs / S_;
        __shared__ float g[M_*P_];
        __shared__ float vis[M_*P_];
        __shared__ float mean_tag[M_];
        __shared__ float validm[M_];
        __shared__ float pull_pp[M_];
        const float* tagbase = preds + ((size_t)bs*CH_ + P_)*HW_;
        if (tid < M_*P_) {
            int m = tid / P_; int p = tid % P_;
            int off = ((b*M_ + m)*P_ + p)*2;
            int idx = kp[off];
            int v   = kp[off+1];
            g[tid]   = tagbase[idx];
            vis[tid] = (v > 0) ? 1.0f : 0.0f;
        }
        __syncthreads();
        if (tid < M_) {
            float cnt = 0.0f, sum = 0.0f;
            for (int p = 0; p < P_; p++) { cnt += vis[tid*P_+p]; sum += g[tid*P_+p]*vis[tid*P_+p]; }
            float safe = fmaxf(cnt, 1.0f);
            float mt = sum / safe;
            mean_tag[tid] = mt;
            validm[tid] = (cnt > 0.0f) ? 1.0f : 0.0f;
            float pp = 0.0f;
            for (int p = 0; p < P_; p++) { float d = g[tid*P_+p] - mt; pp += d*d*vis[tid*P_+p]; }
            pull_pp[tid] = pp / safe;
        }
        __syncthreads();
        if (tid == 0) {
            float num = 0.0f;
            for (int m = 0; m < M_; m++) num += validm[m];
            float pull = 0.0f;
            for (int m = 0; m < M_; m++) pull += pull_pp[m]*validm[m];
            pull = pull / (num + 1e-6f);
            float pmsum = 0.0f;
            for (int i = 0; i < M_; i++)
                for (int j = 0; j < M_; j++) {
                    float d = mean_tag[i] - mean_tag[j]; d = d*d;
                    pmsum += expf(-d)*validm[i]*validm[j];
                }
            float push = (pmsum - num) / ((num - 1.0f)*num + 1e-6f) * 0.5f;
            ws_tag[bs] = push + pull;
        }
    }
}

// ---------------- top-k phase 2: merge 34 lists, compute tv/pid ----------------
__global__ __launch_bounds__(64) void k_top2(const float* __restrict__ preds,
                                             const float* __restrict__ gsk,
                                             const unsigned long long* __restrict__ cand,
                                             float* __restrict__ ws_tv,
                                             int* __restrict__ ws_pid) {
    int bs = blockIdx.x; int b = bs / S_;
    int tid = threadIdx.x;
    __shared__ unsigned long long sm[64*10];
    if (tid < G_) {
        #pragma unroll
        for (int j = 0; j < 10; ++j) sm[tid*10+j] = cand[((size_t)bs*G_ + tid)*10 + j];
    } else {
        #pragma unroll
        for (int j = 0; j < 10; ++j) sm[tid*10+j] = 0ull;
    }
    __syncthreads();
    for (int st = 32; st >= 1; st >>= 1) {
        if (tid < st) {
            unsigned long long x[10], y[10];
            #pragma unroll
            for (int j = 0; j < 10; ++j) { x[j] = sm[tid*10+j]; y[j] = sm[(tid+st)*10+j]; }
            merge10(x, y);
            #pragma unroll
            for (int j = 0; j < 10; ++j) sm[tid*10+j] = x[j];
        }
        __syncthreads();
    }
    if (tid < K_) {
        unsigned long long key = sm[tid];
        unsigned int topi = (unsigned int)(~key);    // recover index
        int part = topi >> 14;                       // / HW_
        int rem  = topi & (HW_-1);
        int xi   = rem >> 7;
        int yi   = rem & (W_-1);
        const float* tagbase = preds + ((size_t)bs*CH_ + P_)*HW_;
        float tv = tagbase[topi];
        float best = INFINITY; int pid = 0;
        for (int m = 0; m < M_; m++) {
            const float* sk = gsk + ((size_t)(b*M_ + m)*P_ + part)*3;
            float sk1 = sk[1], sk2 = sk[2];
            float vp = (sk2 == 1.0f) ? MAXDIST : 0.0f;
            float d0 = vp + sk1 - (float)xi;
            float d1 = vp + sk2 - (float)yi;
            float dist = sqrtf(d0*d0 + d1*d1 + 1e-12f);
            if (dist < best) { best = dist; pid = m; }
        }
        int o = bs*K_ + tid;
        ws_tv[o]  = tv;
        ws_pid[o] = pid;
    }
}

// ------- skel partial: (b,s,p) x 4 chunks, 256 threads, partials to ws -------
__global__ __launch_bounds__(256, 4) void k_skel(const float* __restrict__ preds,
                                                 const float* __restrict__ ws_tv,
                                                 float* __restrict__ ws_skl,
                                                 float* __restrict__ ws_ssx,
                                                 float* __restrict__ ws_ssy) {
    int bid   = blockIdx.x / SKEL_CHUNKS;   // over B*S*P
    int chunk = blockIdx.x % SKEL_CHUNKS;
    int p  = bid % P_;
    int bs = bid / P_;
    const float4* hm4 = (const float4*)(preds + ((size_t)bs*CH_ + p)*HW_);
    const float4* tg4 = (const float4*)(preds + ((size_t)bs*CH_ + P_ + p)*HW_);
    float tv[K_];
    #pragma unroll
    for (int k = 0; k < K_; k++) tv[k] = ws_tv[bs*K_ + k];
    float l[K_], sx[K_], sy[K_];
    #pragma unroll
    for (int k = 0; k < K_; k++) { l[k] = 0.0f; sx[k] = 0.0f; sy[k] = 0.0f; }
    int tid = threadIdx.x;
    const float C2 = INV2SIG * LOG2E;       // exp(z) == exp2(z*log2e)
    #pragma unroll
    for (int j = 0; j < 4; ++j) {           // 4 float4 per thread, 4096 px per chunk
        int q = chunk*1024 + j*256 + tid;   // global float4 index in [0,4096)
        float4 hv = hm4[q];
        float4 tg = tg4[q];
        float h  = (float)(q >> 5);         // row of this float4
        float w0 = (float)((q*4) & (W_-1)); // col of component .x
        const float* hvv = &hv.x; const float* tgv = &tg.x;
        #pragma unroll
        for (int cc = 0; cc < 4; ++cc) {
            float a2 = (SF_*LOG2E) * hvv[cc];
            float tgc = tgv[cc];
            float w = w0 + (float)cc;
            #pragma unroll
            for (int k = 0; k < K_; k++) {
                float d = tgc - tv[k];
                float e = exp2f(fmaf(-C2, d*d, a2));
                l[k] += e;
                sx[k] = fmaf(e, h, sx[k]);
                sy[k] = fmaf(e, w, sy[k]);
            }
        }
    }
    #pragma unroll
    for (int k = 0; k < K_; k++) {
        for (int off = 32; off > 0; off >>= 1) {
            l[k]  += __shfl_down(l[k],  off);
            sx[k] += __shfl_down(sx[k], off);
            sy[k] += __shfl_down(sy[k], off);
        }
    }
    __shared__ float red[4][K_][3];
    int wave = tid >> 6, lane = tid & 63;
    if (lane == 0) {
        #pragma unroll
        for (int k = 0; k < K_; k++) {
            red[wave][k][0] = l[k]; red[wave][k][1] = sx[k]; red[wave][k][2] = sy[k];
        }
    }
    __syncthreads();
    if (tid < K_) {
        int k = tid;
        float L  = red[0][k][0] + red[1][k][0] + red[2][k][0] + red[3][k][0];
        float SX = red[0][k][1] + red[1][k][1] + red[2][k][1] + red[3][k][1];
        float SY = red[0][k][2] + red[1][k][2] + red[2][k][2] + red[3][k][2];
        int o = blockIdx.x*K_ + k;
        ws_skl[o] = L; ws_ssx[o] = SX; ws_ssy[o] = SY;
    }
}

// ---------------- final reduce: det + tag + skel -> out[0] ----------------
__global__ __launch_bounds__(256) void k_fin(const float* __restrict__ gsk,
                                             const int* __restrict__ ws_pid,
                                             const float* __restrict__ ws_skl,
                                             const float* __restrict__ ws_ssx,
                                             const float* __restrict__ ws_ssy,
                                             const float* __restrict__ ws_det,
                                             const float* __restrict__ ws_tag,
                                             float* __restrict__ out) {
    int tid = threadIdx.x;
    float acc = 0.0f;
    // det: mean over all elements
    for (int i = tid; i < DET_BLOCKS; i += 256) acc += ws_det[i];
    acc *= (1.0f/(float)(B_*S_*P_*HW_));
    // tag: mean of per-(b,s) push+pull
    if (tid < B_*S_) acc += ws_tag[tid] * (1.0f/(float)(B_*S_));
    // skel: per (bid,k) combine 4 chunk partials
    for (int idx = tid; idx < NBSP*K_; idx += 256) {
        int bid = idx / K_;
        int k   = idx % K_;
        int p  = bid % P_;
        int bs = bid / P_;
        int b  = bs / S_;
        float L = 0.0f, SX = 0.0f, SY = 0.0f;
        #pragma unroll
        for (int c = 0; c < SKEL_CHUNKS; ++c) {
            int o = (bid*SKEL_CHUNKS + c)*K_ + k;
            L += ws_skl[o]; SX += ws_ssx[o]; SY += ws_ssy[o];
        }
        float px = SX / L, py = SY / L;
        int pid = ws_pid[bs*K_ + k];
        const float* g = gsk + ((size_t)(b*M_ + pid)*P_ + p)*3;
        float d0 = g[0] - px, d1 = g[1] - py;
        float gate = (g[2] > 0.0f) ? 1.0f : 0.0f;
        float err = sqrtf(d0*d0 + d1*d1 + 1e-12f) * gate;
        float hub = (err < 0.1f) ? err*err : 0.1f*(err - 0.05f);
        acc += hub * (10.0f/(float)(B_*S_*K_*P_));
    }
    #pragma unroll
    for (int off = 32; off > 0; off >>= 1) acc += __shfl_down(acc, off);
    __shared__ float sred[4];
    int wave = tid >> 6, lane = tid & 63;
    if (lane == 0) sred[wave] = acc;
    __syncthreads();
    if (tid == 0) out[0] = sred[0] + sred[1] + sred[2] + sred[3];
}

extern "C" void kernel_launch(void* const* d_in, const int* in_sizes, int n_in,
                              void* d_out, int out_size, void* d_ws, size_t ws_size,
                              hipStream_t stream) {
    (void)in_sizes; (void)n_in; (void)out_size; (void)ws_size;
    const float* preds = (const float*)d_in[0];
    const float* gmask = (const float*)d_in[1];
    const float* gh    = (const float*)d_in[2];
    const float* gsk   = (const float*)d_in[3];
    const int*   gkp   = (const int*)d_in[4];
    float* out = (float*)d_out;
    unsigned long long* cand = (unsigned long long*)d_ws;            // 2720 u64
    float* ws_tv  = (float*)(cand + (size_t)B_*S_*G_*10);            // 80 f
    int*   ws_pid = (int*)(ws_tv + (size_t)B_*S_*K_);                // 80 i
    float* ws_skl = (float*)(ws_pid + (size_t)B_*S_*K_);             // 5440 f
    float* ws_ssx = ws_skl + (size_t)SKEL_BLOCKS*K_;                 // 5440 f
    float* ws_ssy = ws_ssx + (size_t)SKEL_BLOCKS*K_;                 // 5440 f
    float* ws_det = ws_ssy + (size_t)SKEL_BLOCKS*K_;                 // 544 f
    float* ws_tag = ws_det + DET_BLOCKS;                             // 8 f

    hipLaunchKernelGGL(k_main, dim3(MAIN_BLOCKS), dim3(256), 0, stream,
                       preds, gmask, gh, gkp, cand, ws_det, ws_tag);
    hipLaunchKernelGGL(k_top2, dim3(B_*S_),       dim3(64),  0, stream,
                       preds, gsk, cand, ws_tv, ws_pid);
    hipLaunchKernelGGL(k_skel, dim3(SKEL_BLOCKS), dim3(256), 0, stream,
                       preds, ws_tv, ws_skl, ws_ssx, ws_ssy);
    hipLaunchKernelGGL(k_fin,  dim3(1),           dim3(256), 0, stream,
                       gsk, ws_pid, ws_skl, ws_ssx, ws_ssy, ws_det, ws_tag, out);
}